// Round 4
// baseline (1590.597 us; speedup 1.0000x reference)
//
#include <hip/hip_runtime.h>

#define N_MET 100000
#define N_RXN 50000
#define E_SUB 2000000
#define E_ALL 4000000
#define MSG_DIM 16
#define HIDDEN 32

// ---- Phase 1: build CSR of substrate edges by reaction (counting sort), ----
// ---- then gather-reduce per reaction. Atomics: 4M int (vs 32M f32). ---------

// 1a. histogram of rxn_sub (int4-vectorized reads; E_SUB % 4 == 0)
__global__ __launch_bounds__(256) void hist_kernel(
    const int* __restrict__ rxn_sub, int* __restrict__ count)
{
    const int i = blockIdx.x * 256 + threadIdx.x;
    if (i >= E_SUB / 4) return;
    const int4 r = ((const int4*)rxn_sub)[i];
    atomicAdd(&count[r.x], 1);
    atomicAdd(&count[r.y], 1);
    atomicAdd(&count[r.z], 1);
    atomicAdd(&count[r.w], 1);
}

// 1b. exclusive scan of count[N_RXN] -> row_ptr[N_RXN+1], and next = row_ptr.
// Single block, 1024 threads, shfl-based wave scan + cross-wave LDS scan.
__global__ __launch_bounds__(1024) void scan_kernel(
    const int* __restrict__ count, int* __restrict__ row_ptr,
    int* __restrict__ next)
{
    __shared__ int wsum[16];
    const int t = threadIdx.x;
    const int lane = t & 63;
    const int w = t >> 6;
    int carry = 0;                       // uniform across all threads
    for (int base = 0; base < N_RXN; base += 1024) {
        const int idx = base + t;
        const int val = (idx < N_RXN) ? count[idx] : 0;
        // wave-inclusive scan
        int x = val;
#pragma unroll
        for (int off = 1; off < 64; off <<= 1) {
            const int y = __shfl_up(x, off);
            if (lane >= off) x += y;
        }
        if (lane == 63) wsum[w] = x;
        __syncthreads();
        if (w == 0) {
            int s = (lane < 16) ? wsum[lane] : 0;
#pragma unroll
            for (int off = 1; off < 16; off <<= 1) {
                const int y = __shfl_up(s, off);
                if (lane >= off) s += y;
            }
            if (lane < 16) wsum[lane] = s;
        }
        __syncthreads();
        const int wexcl = (w > 0) ? wsum[w - 1] : 0;
        const int excl = wexcl + x - val;
        if (idx < N_RXN) {
            const int rp = carry + excl;
            row_ptr[idx] = rp;
            next[idx] = rp;
        }
        carry += wsum[15];
        __syncthreads();                 // protect wsum before next chunk
    }
    if (t == 0) row_ptr[N_RXN] = carry;  // == E_SUB
}

// 1c. placement: slot = next[r]++ ; edges_sorted[slot] = {x_met[met], sto}
__global__ __launch_bounds__(256) void place_kernel(
    const float* __restrict__ x_met, const float* __restrict__ sto_sub,
    const int* __restrict__ met_sub, const int* __restrict__ rxn_sub,
    int* __restrict__ next, float2* __restrict__ edges_sorted)
{
    const int e = blockIdx.x * 256 + threadIdx.x;
    if (e >= E_SUB) return;
    const int r = rxn_sub[e];
    const int slot = atomicAdd(&next[r], 1);
    edges_sorted[slot] = make_float2(x_met[met_sub[e]], sto_sub[e]);
}

// 1d. fused gather + msg-MLP + rate-MLP + softplus -> v[N_RXN]. No atomics.
__global__ __launch_bounds__(256) void gather_rate_kernel(
    const float2* __restrict__ edges_sorted, const int* __restrict__ row_ptr,
    const float* __restrict__ W1m, const float* __restrict__ b1m,
    const float* __restrict__ W2m, const float* __restrict__ b2m,
    const float* __restrict__ W1r, const float* __restrict__ b1r,
    const float* __restrict__ W2r, const float* __restrict__ b2r,
    float* __restrict__ v)
{
    __shared__ float sW1m[2 * HIDDEN];
    __shared__ float sb1m[HIDDEN];
    __shared__ float sW2m[HIDDEN * MSG_DIM];
    __shared__ float sb2m[MSG_DIM];
    __shared__ float sW1r[MSG_DIM * HIDDEN];
    __shared__ float sb1r[HIDDEN];
    __shared__ float sW2r[HIDDEN];
    __shared__ float sb2r;
    const int t = threadIdx.x;
    if (t < 2 * HIDDEN) sW1m[t] = W1m[t];
    if (t < HIDDEN)     sb1m[t] = b1m[t];
    for (int i = t; i < HIDDEN * MSG_DIM; i += 256) sW2m[i] = W2m[i];
    if (t < MSG_DIM)    sb2m[t] = b2m[t];
    for (int i = t; i < MSG_DIM * HIDDEN; i += 256) sW1r[i] = W1r[i];
    if (t >= 64 && t < 64 + HIDDEN) { sb1r[t - 64] = b1r[t - 64]; sW2r[t - 64] = W2r[t - 64]; }
    if (t == 128) sb2r = b2r[0];
    __syncthreads();

    const int r = blockIdx.x * 256 + t;
    if (r >= N_RXN) return;

    const int beg = row_ptr[r];
    const int end = row_ptr[r + 1];

    float h[MSG_DIM];
#pragma unroll
    for (int d = 0; d < MSG_DIM; ++d) h[d] = 0.0f;

    for (int i = beg; i < end; ++i) {
        const float2 xs = edges_sorted[i];
#pragma unroll
        for (int j = 0; j < HIDDEN; ++j) {
            const float hj =
                tanhf(fmaf(xs.x, sW1m[j], fmaf(xs.y, sW1m[HIDDEN + j], sb1m[j])));
#pragma unroll
            for (int d = 0; d < MSG_DIM; ++d)
                h[d] = fmaf(hj, sW2m[j * MSG_DIM + d], h[d]);
        }
    }
    // fold per-edge +b2m: sum over cnt edges = cnt * b2m
    const float cnt = (float)(end - beg);
#pragma unroll
    for (int d = 0; d < MSG_DIM; ++d) h[d] = fmaf(cnt, sb2m[d], h[d]);

    float acc = sb2r;
#pragma unroll
    for (int j = 0; j < HIDDEN; ++j) {
        float z = sb1r[j];
#pragma unroll
        for (int d = 0; d < MSG_DIM; ++d) z = fmaf(h[d], sW1r[d * HIDDEN + j], z);
        acc = fmaf(tanhf(z), sW2r[j], acc);
    }
    v[r] = fmaxf(acc, 0.0f) + log1pf(expf(-fabsf(acc)));
}

// ---- Phase 2: per-all-edge contribution scattered into dxdt (4M atomics —
// minimal atomic formulation for this side; CSR here would cost 8M). ----------
__global__ __launch_bounds__(256) void contrib_scatter_kernel(
    const float* __restrict__ sto_all, const float* __restrict__ v,
    const int* __restrict__ met_all, const int* __restrict__ rxn_all,
    float* __restrict__ dxdt)
{
    const int e = blockIdx.x * 256 + threadIdx.x;
    if (e >= E_ALL) return;
    const float c = sto_all[e] * v[rxn_all[e]];
    unsafeAtomicAdd(dxdt + met_all[e], c);
}

extern "C" void kernel_launch(void* const* d_in, const int* in_sizes, int n_in,
                              void* d_out, int out_size, void* d_ws, size_t ws_size,
                              hipStream_t stream) {
    const float* x_met   = (const float*)d_in[0];
    const float* sto_sub = (const float*)d_in[1];
    const float* sto_all = (const float*)d_in[2];
    const float* W1m     = (const float*)d_in[3];
    const float* b1m     = (const float*)d_in[4];
    const float* W2m     = (const float*)d_in[5];
    const float* b2m     = (const float*)d_in[6];
    const float* W1r     = (const float*)d_in[7];
    const float* b1r     = (const float*)d_in[8];
    const float* W2r     = (const float*)d_in[9];
    const float* b2r     = (const float*)d_in[10];
    const int*   met_sub = (const int*)d_in[11];
    const int*   rxn_sub = (const int*)d_in[12];
    const int*   met_all = (const int*)d_in[13];
    const int*   rxn_all = (const int*)d_in[14];

    float* dxdt = (float*)d_out;             // [N_MET]
    float* v    = dxdt + N_MET;              // [N_RXN]

    // workspace layout
    char* ws = (char*)d_ws;
    int* count   = (int*)ws;                              ws += sizeof(int) * N_RXN;
    int* row_ptr = (int*)ws;                              ws += sizeof(int) * (N_RXN + 1);
    int* next    = (int*)ws;                              ws += sizeof(int) * N_RXN;
    float2* edges_sorted = (float2*)ws;                   // [E_SUB] = 16 MB

    hipMemsetAsync(count, 0, sizeof(int) * N_RXN, stream);
    hipMemsetAsync(dxdt, 0, sizeof(float) * N_MET, stream);

    hist_kernel<<<(E_SUB / 4 + 255) / 256, 256, 0, stream>>>(rxn_sub, count);
    scan_kernel<<<1, 1024, 0, stream>>>(count, row_ptr, next);
    place_kernel<<<(E_SUB + 255) / 256, 256, 0, stream>>>(
        x_met, sto_sub, met_sub, rxn_sub, next, edges_sorted);
    gather_rate_kernel<<<(N_RXN + 255) / 256, 256, 0, stream>>>(
        edges_sorted, row_ptr, W1m, b1m, W2m, b2m, W1r, b1r, W2r, b2r, v);
    contrib_scatter_kernel<<<(E_ALL + 255) / 256, 256, 0, stream>>>(
        sto_all, v, met_all, rxn_all, dxdt);
}